// Round 5
// baseline (431.786 us; speedup 1.0000x reference)
//
#include <hip/hip_runtime.h>
#include <hip/hip_bf16.h>

#define NN 20000
#define EE 640000

typedef __attribute__((ext_vector_type(8))) short bf16x8;
typedef __attribute__((ext_vector_type(4))) float f32x4;

__device__ __forceinline__ ushort f2b(float f) {
    __hip_bfloat16 h = __float2bfloat16(f);
    return *(ushort*)&h;
}
__device__ __forceinline__ float b2f(ushort u) {
    __hip_bfloat16 h = *(__hip_bfloat16*)&u;
    return __bfloat162float(h);
}

// ---------------- CSR build ----------------

__global__ void init_cnt_kernel(int* __restrict__ cnt, int n) {
    int i = blockIdx.x * 256 + threadIdx.x;
    if (i < n) cnt[i] = 0;
}

__global__ void hist_kernel(const int* __restrict__ col, int* __restrict__ cnt, int e) {
    int i = blockIdx.x * 256 + threadIdx.x;
    if (i < e) atomicAdd(&cnt[col[i]], 1);
}

__global__ void dinv_kernel(const int* __restrict__ cnt, float* __restrict__ dinv, int n) {
    int i = blockIdx.x * 256 + threadIdx.x;
    if (i < n) dinv[i] = rsqrtf((float)(cnt[i] + 1));  // +1 self-loop; always > 0
}

// in-block exclusive scan helper (256 threads)
__device__ __forceinline__ int block_exscan(int v) {
    __shared__ int wsum[4];
    int tid = threadIdx.x, lane = tid & 63, w = tid >> 6;
    int x = v;
    #pragma unroll
    for (int d = 1; d < 64; d <<= 1) {
        int y = __shfl_up(x, d, 64);
        if (lane >= d) x += y;
    }
    if (lane == 63) wsum[w] = x;
    __syncthreads();
    if (tid == 0) {
        int s = 0;
        #pragma unroll
        for (int k = 0; k < 4; ++k) { int t = wsum[k]; wsum[k] = s; s += t; }
    }
    __syncthreads();
    return wsum[w] + x - v;
}

__global__ __launch_bounds__(256) void scan_p1_kernel(const int* __restrict__ cnt,
                                                      int* __restrict__ offs,
                                                      int* __restrict__ bsum, int n) {
    int i = blockIdx.x * 256 + threadIdx.x;
    int v = (i < n) ? cnt[i] : 0;
    int e = block_exscan(v);
    if (i < n) offs[i] = e;
    if (threadIdx.x == 255) bsum[blockIdx.x] = e + v;
}

__global__ __launch_bounds__(256) void scan_p2_kernel(int* __restrict__ bsum, int nblk) {
    int t = threadIdx.x;
    int v = (t < nblk) ? bsum[t] : 0;
    int e = block_exscan(v);
    if (t < nblk) bsum[t] = e;
}

__global__ __launch_bounds__(256) void scan_p3_kernel(int* __restrict__ offs,
                                                      const int* __restrict__ bsum,
                                                      int* __restrict__ cursor, int n) {
    int i = blockIdx.x * 256 + threadIdx.x;
    if (i < n) {
        int o = offs[i] + bsum[blockIdx.x];
        offs[i] = o;
        cursor[i] = o;
    }
}

__global__ void scatter_kernel(const int* __restrict__ row, const int* __restrict__ col,
                               const float* __restrict__ dinv, int* __restrict__ cursor,
                               int2* __restrict__ pair, int e) {
    int i = blockIdx.x * 256 + threadIdx.x;
    if (i >= e) return;
    int s = row[i], d = col[i];
    int pos = atomicAdd(&cursor[d], 1);
    int2 p;
    p.x = s;
    p.y = __float_as_int(dinv[s] * dinv[d]);
    pair[pos] = p;
}

// ---------------- sort each node's edge segment by source (wave bitonic, <=64) ----------------
__global__ __launch_bounds__(256) void sort_kernel(
    const int* __restrict__ offs, const int* __restrict__ cnt,
    int2* __restrict__ pair, int n) {
    int node = blockIdx.x * 4 + (threadIdx.x >> 6);
    int lane = threadIdx.x & 63;
    if (node >= n) return;
    int beg = offs[node], num = cnt[node];
    if (num <= 1 || num > 64) return;   // >64 is vanishingly rare; sort is perf-only
    unsigned long long key = ~0ULL;
    if (lane < num) {
        int2 p = pair[beg + lane];
        key = ((unsigned long long)(unsigned)p.x << 32) | (unsigned)p.y;
    }
    #pragma unroll
    for (int k = 2; k <= 64; k <<= 1) {
        #pragma unroll
        for (int j = k >> 1; j >= 1; j >>= 1) {
            unsigned long long other = __shfl_xor(key, j, 64);
            bool up = ((lane & k) == 0) == ((lane & j) == 0);
            unsigned long long mn = other < key ? other : key;
            unsigned long long mx = other < key ? key : other;
            key = up ? mn : mx;
        }
    }
    if (lane < num) {
        int2 p;
        p.x = (int)(key >> 32);
        p.y = (int)(unsigned)(key & 0xffffffffu);
        pair[beg + lane] = p;
    }
}

// ---------------- weight prep: W [256][256] f32 -> Wt [256 col][768 kv] bf16 ----------------
__global__ __launch_bounds__(256) void wprep_kernel(const float* __restrict__ W,
                                                    ushort* __restrict__ Wt) {
    int col = blockIdx.x;
    for (int kv = threadIdx.x; kv < 768; kv += 256) {
        int k = kv & 255;
        float w = W[(size_t)k * 256 + col];
        ushort hi = f2b(w);
        ushort out = (kv < 256 || kv >= 512) ? hi : f2b(w - b2f(hi));
        Wt[(size_t)col * 768 + kv] = out;
    }
}

// ---------------- aggregation v4: wave per node, full 256-feat rows, sorted gathers ----------------
// Output: a2 [n][512] bf16 — cols 0..255 hi, 256..511 lo.
__global__ __launch_bounds__(256) void agg_kernel(
    const float* __restrict__ h,
    const int* __restrict__ offs, const int* __restrict__ cnt,
    const int2* __restrict__ pair,
    const float* __restrict__ dinv,
    ushort* __restrict__ a2, int n) {
    int node = blockIdx.x * 4 + (threadIdx.x >> 6);
    int lane = threadIdx.x & 63;
    const float4* hv = (const float4*)h;   // row r, lane: hv[r*64 + lane]

    int beg = offs[node], num = cnt[node];
    float4 acc = {0.f, 0.f, 0.f, 0.f};

    int j = 0;
    for (; j + 4 <= num; j += 4) {
        int2 e0 = pair[beg + j];
        int2 e1 = pair[beg + j + 1];
        int2 e2 = pair[beg + j + 2];
        int2 e3 = pair[beg + j + 3];
        float4 v0 = hv[(size_t)e0.x * 64 + lane];
        float4 v1 = hv[(size_t)e1.x * 64 + lane];
        float4 v2 = hv[(size_t)e2.x * 64 + lane];
        float4 v3 = hv[(size_t)e3.x * 64 + lane];
        float m0 = __int_as_float(e0.y), m1 = __int_as_float(e1.y);
        float m2 = __int_as_float(e2.y), m3 = __int_as_float(e3.y);
        acc.x = fmaf(m0, v0.x, acc.x); acc.y = fmaf(m0, v0.y, acc.y);
        acc.z = fmaf(m0, v0.z, acc.z); acc.w = fmaf(m0, v0.w, acc.w);
        acc.x = fmaf(m1, v1.x, acc.x); acc.y = fmaf(m1, v1.y, acc.y);
        acc.z = fmaf(m1, v1.z, acc.z); acc.w = fmaf(m1, v1.w, acc.w);
        acc.x = fmaf(m2, v2.x, acc.x); acc.y = fmaf(m2, v2.y, acc.y);
        acc.z = fmaf(m2, v2.z, acc.z); acc.w = fmaf(m2, v2.w, acc.w);
        acc.x = fmaf(m3, v3.x, acc.x); acc.y = fmaf(m3, v3.y, acc.y);
        acc.z = fmaf(m3, v3.z, acc.z); acc.w = fmaf(m3, v3.w, acc.w);
    }
    for (; j < num; ++j) {
        int2 e0 = pair[beg + j];
        float m0 = __int_as_float(e0.y);
        float4 v0 = hv[(size_t)e0.x * 64 + lane];
        acc.x = fmaf(m0, v0.x, acc.x); acc.y = fmaf(m0, v0.y, acc.y);
        acc.z = fmaf(m0, v0.z, acc.z); acc.w = fmaf(m0, v0.w, acc.w);
    }

    float di = dinv[node];
    float sn = di * di;
    float4 self = hv[(size_t)node * 64 + lane];
    acc.x = fmaf(sn, self.x, acc.x); acc.y = fmaf(sn, self.y, acc.y);
    acc.z = fmaf(sn, self.z, acc.z); acc.w = fmaf(sn, self.w, acc.w);

    ushort4 hi, lo;
    hi.x = f2b(acc.x); lo.x = f2b(acc.x - b2f(hi.x));
    hi.y = f2b(acc.y); lo.y = f2b(acc.y - b2f(hi.y));
    hi.z = f2b(acc.z); lo.z = f2b(acc.z - b2f(hi.z));
    hi.w = f2b(acc.w); lo.w = f2b(acc.w - b2f(hi.w));
    *(ushort4*)(a2 + (size_t)node * 512 + lane * 4)       = hi;
    *(ushort4*)(a2 + (size_t)node * 512 + 256 + lane * 4) = lo;
}

// ---------------- bf16 MFMA GEMM: C = A'' @ W'' (+bias, opt ReLU), 128x64 tile ----------------
template<bool RELU>
__global__ __launch_bounds__(256) void gemm_mfma_kernel(
    const ushort* __restrict__ A2, const ushort* __restrict__ Wt,
    const float* __restrict__ bias, float* __restrict__ C, int n) {
    __shared__ ushort Ast[128][72];
    __shared__ ushort Bst[64][72];
    int tid = threadIdx.x;
    int lane = tid & 63, wid = tid >> 6;
    int rowbase = blockIdx.x * 128;
    int colbase = blockIdx.y * 64;
    int awr = wid * 32;

    f32x4 zero = {0.f, 0.f, 0.f, 0.f};
    f32x4 acc[2][4];
    #pragma unroll
    for (int m = 0; m < 2; ++m)
        #pragma unroll
        for (int nn = 0; nn < 4; ++nn) acc[m][nn] = zero;

    int rA = tid >> 1;             // 0..127
    int sA = (tid & 1) * 32;       // half-row of 32 shorts
    int grA = min(rowbase + rA, n - 1);
    const ushort* aRow = A2 + (size_t)grA * 512;
    int rB = tid >> 2;             // 0..63
    int sB = (tid & 3) * 16;       // quarter-row of 16 shorts
    const ushort* bRow = Wt + (size_t)(colbase + rB) * 768;

    for (int kt = 0; kt < 12; ++kt) {
        int kv0 = kt * 64;
        int acol0 = (kv0 < 256) ? kv0 : kv0 - 256;
        #pragma unroll
        for (int q = 0; q < 4; ++q)
            *(float4*)(&Ast[rA][sA + q * 8]) =
                *(const float4*)(aRow + acol0 + sA + q * 8);
        #pragma unroll
        for (int q = 0; q < 2; ++q)
            *(float4*)(&Bst[rB][sB + q * 8]) =
                *(const float4*)(bRow + kv0 + sB + q * 8);
        __syncthreads();
        #pragma unroll
        for (int kk = 0; kk < 2; ++kk) {
            int ko = kk * 32 + (lane >> 4) * 8;
            bf16x8 af[2], bf[4];
            #pragma unroll
            for (int m = 0; m < 2; ++m)
                af[m] = *(const bf16x8*)&Ast[awr + m * 16 + (lane & 15)][ko];
            #pragma unroll
            for (int nn = 0; nn < 4; ++nn)
                bf[nn] = *(const bf16x8*)&Bst[nn * 16 + (lane & 15)][ko];
            #pragma unroll
            for (int m = 0; m < 2; ++m)
                #pragma unroll
                for (int nn = 0; nn < 4; ++nn)
                    acc[m][nn] = __builtin_amdgcn_mfma_f32_16x16x32_bf16(
                        af[m], bf[nn], acc[m][nn], 0, 0, 0);
        }
        __syncthreads();
    }

    #pragma unroll
    for (int nn = 0; nn < 4; ++nn) {
        int col = colbase + nn * 16 + (lane & 15);
        float bv = bias[col];
        #pragma unroll
        for (int m = 0; m < 2; ++m) {
            int grow0 = rowbase + awr + m * 16 + ((lane >> 4) << 2);
            f32x4 v = acc[m][nn];
            #pragma unroll
            for (int r = 0; r < 4; ++r) {
                int row = grow0 + r;
                if (row < n) {
                    float val = v[r] + bv;
                    if (RELU) val = fmaxf(val, 0.f);
                    C[(size_t)row * 256 + col] = val;
                }
            }
        }
    }
}

// ---------------- final projection: out[i] = h3[i,:] . Wout + bout ----------------
__global__ __launch_bounds__(256) void out_kernel(
    const float* __restrict__ h3, const float* __restrict__ Wout,
    const float* __restrict__ bout, float* __restrict__ out, int n) {
    int node = blockIdx.x * 4 + (threadIdx.x >> 6);
    int lane = threadIdx.x & 63;
    if (node >= n) return;
    float4 v = ((const float4*)(h3 + (size_t)node * 256))[lane];
    float4 w = ((const float4*)Wout)[lane];
    float sum = v.x * w.x + v.y * w.y + v.z * w.z + v.w * w.w;
    #pragma unroll
    for (int d = 32; d > 0; d >>= 1) sum += __shfl_down(sum, d, 64);
    if (lane == 0) out[node] = sum + bout[0];
}

extern "C" void kernel_launch(void* const* d_in, const int* in_sizes, int n_in,
                              void* d_out, int out_size, void* d_ws, size_t ws_size,
                              hipStream_t stream) {
    const int n = NN, e = EE;
    const float* x    = (const float*)d_in[0];
    const int*   eidx = (const int*)d_in[1];
    const float* W1   = (const float*)d_in[2];
    const float* b1   = (const float*)d_in[3];
    const float* Wh   = (const float*)d_in[4];
    const float* bh   = (const float*)d_in[5];
    const float* W2   = (const float*)d_in[6];
    const float* b2   = (const float*)d_in[7];
    const float* Wout = (const float*)d_in[8];
    const float* bout = (const float*)d_in[9];
    const int* row = eidx;        // sources
    const int* col = eidx + e;    // destinations

    char* ws = (char*)d_ws;
    int*    cnt     = (int*)ws;    ws += (size_t)n * 4;
    int*    offs    = (int*)ws;    ws += (size_t)n * 4;
    int*    cursor  = (int*)ws;    ws += (size_t)n * 4;
    float*  dinv    = (float*)ws;  ws += (size_t)n * 4;
    int*    bsum    = (int*)ws;    ws += (size_t)256 * 4;
    int2*   pair    = (int2*)ws;   ws += (size_t)e * 8;
    float*  buf     = (float*)ws;  ws += (size_t)n * 256 * 4;   // hidden state [n][256]
    ushort* a2      = (ushort*)ws; ws += (size_t)n * 512 * 2;   // A'' hi|lo [n][512]
    ushort* wt1     = (ushort*)ws; ws += (size_t)256 * 768 * 2;
    ushort* wt2     = (ushort*)ws; ws += (size_t)256 * 768 * 2;
    ushort* wt3     = (ushort*)ws; ws += (size_t)256 * 768 * 2;

    float* outv = (float*)d_out;
    float* h3   = (float*)d_out + n;

    int nb_n = (n + 255) / 256;     // 79
    int nb_e = (e + 255) / 256;

    // CSR build (+ per-node source sort for gather locality)
    init_cnt_kernel<<<nb_n, 256, 0, stream>>>(cnt, n);
    hist_kernel<<<nb_e, 256, 0, stream>>>(col, cnt, e);
    dinv_kernel<<<nb_n, 256, 0, stream>>>(cnt, dinv, n);
    scan_p1_kernel<<<nb_n, 256, 0, stream>>>(cnt, offs, bsum, n);
    scan_p2_kernel<<<1, 256, 0, stream>>>(bsum, nb_n);
    scan_p3_kernel<<<nb_n, 256, 0, stream>>>(offs, bsum, cursor, n);
    scatter_kernel<<<nb_e, 256, 0, stream>>>(row, col, dinv, cursor, pair, e);
    sort_kernel<<<(n + 3) / 4, 256, 0, stream>>>(offs, cnt, pair, n);

    // weight prep
    wprep_kernel<<<256, 256, 0, stream>>>(W1, wt1);
    wprep_kernel<<<256, 256, 0, stream>>>(Wh, wt2);
    wprep_kernel<<<256, 256, 0, stream>>>(W2, wt3);

    int agrid = (n + 3) / 4;           // 5000 blocks, wave per node
    dim3 ggrid((n + 127) / 128, 4);    // (157, 4) = 628 blocks

    // layer 1 (agg reads x directly)
    agg_kernel<<<agrid, 256, 0, stream>>>(x, offs, cnt, pair, dinv, a2, n);
    gemm_mfma_kernel<true><<<ggrid, 256, 0, stream>>>(a2, wt1, b1, buf, n);
    // layer 2
    agg_kernel<<<agrid, 256, 0, stream>>>(buf, offs, cnt, pair, dinv, a2, n);
    gemm_mfma_kernel<true><<<ggrid, 256, 0, stream>>>(a2, wt2, bh, buf, n);
    // layer 3 -> h3 straight into d_out
    agg_kernel<<<agrid, 256, 0, stream>>>(buf, offs, cnt, pair, dinv, a2, n);
    gemm_mfma_kernel<false><<<ggrid, 256, 0, stream>>>(a2, wt3, b2, h3, n);
    // decoder
    out_kernel<<<(n + 3) / 4, 256, 0, stream>>>(h3, Wout, bout, outv, n);
}